// Round 1
// baseline (337.613 us; speedup 1.0000x reference)
//
#include <hip/hip_runtime.h>

typedef unsigned short u16;
typedef __attribute__((ext_vector_type(8))) short bf16x8;
typedef __attribute__((ext_vector_type(4))) float f32x4;

#define NROWS 131072
#define NMOL  2048
#define CIN   128
#define HDIM  1024
#define BM    64
#define EMBSTRIDE 1152   // 9*128

// ---------- helpers ----------
__device__ __forceinline__ u16 f2bf(float f) {
    union { float f; unsigned u; } v; v.f = f;
    unsigned u = v.u;
    u += 0x7FFFu + ((u >> 16) & 1u);   // round-to-nearest-even
    return (u16)(u >> 16);
}

__device__ __forceinline__ float silu_f(float v) {
    float e = __expf(-v);
    return v * __builtin_amdgcn_rcpf(1.0f + e);
}

__device__ __forceinline__ f32x4 mfma16(bf16x8 a, bf16x8 b, f32x4 c) {
    return __builtin_amdgcn_mfma_f32_16x16x32_bf16(a, b, c, 0, 0, 0);
}

// ---------- pre-pass: pack W (K x N, fp32 row-major) into bf16 MFMA B-fragments ----------
// frag id = nt*KT + kt ; within frag: lane l, elem j  ->  W[kt*32 + (l>>4)*8 + j][nt*16 + (l&15)]
__global__ void pack_w(const float* __restrict__ W, u16* __restrict__ dst, int K, int N) {
    int tid  = blockIdx.x * blockDim.x + threadIdx.x;
    int lane = tid & 63;
    int frag = tid >> 6;
    int KT = K >> 5;
    int NT = N >> 4;
    if (frag >= KT * NT) return;
    int kt = frag % KT;
    int nt = frag / KT;
    int col  = (nt << 4) + (lane & 15);
    int krow = (kt << 5) + ((lane >> 4) << 3);
    __align__(16) u16 tmp[8];
    #pragma unroll
    for (int j = 0; j < 8; ++j) tmp[j] = f2bf(W[(size_t)(krow + j) * N + col]);
    *reinterpret_cast<uint4*>(dst + (size_t)tid * 8) = *reinterpret_cast<uint4*>(tmp);
}

// ---------- fused MLP: x(64x128) -> silu(xW1+b1) -> silu(hW2+b2) -> dot W3 -> node energy ----------
__global__ __launch_bounds__(512, 2) void fused_mlp(
    const float* __restrict__ emb,
    const u16*  __restrict__ w1f,
    const u16*  __restrict__ w2f,
    const float* __restrict__ b1,
    const float* __restrict__ b2,
    const float* __restrict__ w3,
    const float* __restrict__ b3,
    float* __restrict__ node_e)
{
    __shared__ u16  x_lds[BM][CIN + 8];     // 64 x 136 bf16  (pad 8 -> 2-way-free banks)
    __shared__ u16  h1_lds[BM][HDIM + 8];   // 64 x 1032 bf16
    __shared__ float e_red[8][BM];          // per-wave energy partials

    const int tid  = threadIdx.x;
    const int lane = tid & 63;
    const int w    = tid >> 6;              // wave 0..7
    const int row0 = blockIdx.x * BM;

    // ---- phase 0: stage x tile as bf16 ----
    {
        int r   = tid >> 3;                 // 0..63
        int seg = tid & 7;                  // 8 segs of 16 floats
        const float4* s4 = reinterpret_cast<const float4*>(
            emb + (size_t)(row0 + r) * EMBSTRIDE + seg * 16);
        __align__(16) u16 u[16];
        #pragma unroll
        for (int i = 0; i < 4; ++i) {
            float4 f = s4[i];
            u[i*4+0] = f2bf(f.x); u[i*4+1] = f2bf(f.y);
            u[i*4+2] = f2bf(f.z); u[i*4+3] = f2bf(f.w);
        }
        uint4* d = reinterpret_cast<uint4*>(&x_lds[r][seg * 16]);
        d[0] = reinterpret_cast<uint4*>(u)[0];
        d[1] = reinterpret_cast<uint4*>(u)[1];
        reinterpret_cast<float*>(e_red)[tid] = 0.0f;   // 512 floats == 8*64
    }
    __syncthreads();

    // ---- phase 1: h1 = silu(x @ W1 + b1) ; wave w covers cols [w*128, w*128+128) ----
    {
        bf16x8 a1[4][4];                                   // [mt][kt] all of this block's A
        #pragma unroll
        for (int mt = 0; mt < 4; ++mt)
            #pragma unroll
            for (int kt = 0; kt < 4; ++kt)
                a1[mt][kt] = *reinterpret_cast<const bf16x8*>(
                    &x_lds[mt*16 + (lane & 15)][kt*32 + ((lane >> 4) << 3)]);

        #pragma unroll
        for (int ntl = 0; ntl < 8; ++ntl) {
            int nt  = w * 8 + ntl;
            int col = nt * 16 + (lane & 15);
            float bias = b1[col];
            f32x4 acc[4];
            #pragma unroll
            for (int mt = 0; mt < 4; ++mt) acc[mt] = (f32x4){0.f, 0.f, 0.f, 0.f};
            #pragma unroll
            for (int kt = 0; kt < 4; ++kt) {
                bf16x8 bfrag = *reinterpret_cast<const bf16x8*>(
                    w1f + ((size_t)(nt * 4 + kt) * 64 + lane) * 8);
                #pragma unroll
                for (int mt = 0; mt < 4; ++mt)
                    acc[mt] = mfma16(a1[mt][kt], bfrag, acc[mt]);
            }
            #pragma unroll
            for (int mt = 0; mt < 4; ++mt)
                #pragma unroll
                for (int j = 0; j < 4; ++j) {
                    float s = silu_f(acc[mt][j] + bias);
                    h1_lds[mt*16 + (lane >> 4)*4 + j][col] = f2bf(s);
                }
        }
    }
    __syncthreads();

    // ---- phase 2: h2 = silu(h1 @ W2 + b2), fold (h2 . W3) into per-row energy ----
    float e_lane[16];
    #pragma unroll
    for (int i = 0; i < 16; ++i) e_lane[i] = 0.0f;

    const u16* aptr = &h1_lds[lane & 15][(lane >> 4) << 3];

    #pragma unroll
    for (int c = 0; c < 2; ++c) {
        int ntbase = w * 8 + c * 4;
        f32x4 acc[4][4];                                   // [mt][nti]
        #pragma unroll
        for (int mt = 0; mt < 4; ++mt)
            #pragma unroll
            for (int nti = 0; nti < 4; ++nti) acc[mt][nti] = (f32x4){0.f, 0.f, 0.f, 0.f};

        #pragma unroll 2
        for (int kt = 0; kt < 32; ++kt) {
            bf16x8 a[4];
            #pragma unroll
            for (int mt = 0; mt < 4; ++mt)
                a[mt] = *reinterpret_cast<const bf16x8*>(aptr + mt*16*(HDIM+8) + kt*32);
            #pragma unroll
            for (int nti = 0; nti < 4; ++nti) {
                bf16x8 b = *reinterpret_cast<const bf16x8*>(
                    w2f + (((size_t)(ntbase + nti) * 32 + kt) * 64 + lane) * 8);
                #pragma unroll
                for (int mt = 0; mt < 4; ++mt)
                    acc[mt][nti] = mfma16(a[mt], b, acc[mt][nti]);
            }
        }
        #pragma unroll
        for (int nti = 0; nti < 4; ++nti) {
            int col = (ntbase + nti) * 16 + (lane & 15);
            float bias = b2[col];
            float w3v  = w3[col];
            #pragma unroll
            for (int mt = 0; mt < 4; ++mt)
                #pragma unroll
                for (int j = 0; j < 4; ++j) {
                    float s = silu_f(acc[mt][nti][j] + bias);
                    e_lane[mt*4 + j] += s * w3v;
                }
        }
    }

    // reduce over the 16 lanes of each k-group (lane&15 varies, lane>>4 fixed)
    #pragma unroll
    for (int off = 1; off < 16; off <<= 1)
        #pragma unroll
        for (int i = 0; i < 16; ++i)
            e_lane[i] += __shfl_xor(e_lane[i], off, 64);

    if ((lane & 15) == 0) {
        int g = lane >> 4;
        #pragma unroll
        for (int mt = 0; mt < 4; ++mt)
            #pragma unroll
            for (int j = 0; j < 4; ++j)
                e_red[w][mt*16 + g*4 + j] = e_lane[mt*4 + j];
    }
    __syncthreads();

    if (tid < BM) {
        float s = 0.0f;
        #pragma unroll
        for (int ww = 0; ww < 8; ++ww) s += e_red[ww][tid];
        node_e[row0 + tid] = s + b3[0];
    }
}

// ---------- deterministic segment sum over sorted batch ----------
__global__ void segsum(const float* __restrict__ node_e,
                       const int* __restrict__ batch,
                       float* __restrict__ out)
{
    int mol  = blockIdx.x;
    int lane = threadIdx.x;          // 64 threads

    int lo = 0, hi = NROWS;
    while (lo < hi) { int mid = (lo + hi) >> 1; if (batch[mid] < mol)     lo = mid + 1; else hi = mid; }
    int start = lo;
    lo = start; hi = NROWS;
    while (lo < hi) { int mid = (lo + hi) >> 1; if (batch[mid] < mol + 1) lo = mid + 1; else hi = mid; }
    int end = lo;

    float s = 0.0f;
    for (int i = start + lane; i < end; i += 64) s += node_e[i];
    #pragma unroll
    for (int off = 32; off; off >>= 1) s += __shfl_xor(s, off, 64);
    if (lane == 0) out[mol] = s;
}

// ---------- launch ----------
extern "C" void kernel_launch(void* const* d_in, const int* in_sizes, int n_in,
                              void* d_out, int out_size, void* d_ws, size_t ws_size,
                              hipStream_t stream) {
    const float* emb = (const float*)d_in[0];
    const float* W1  = (const float*)d_in[1];
    const float* b1  = (const float*)d_in[2];
    const float* W2  = (const float*)d_in[3];
    const float* b2  = (const float*)d_in[4];
    const float* W3  = (const float*)d_in[5];
    const float* b3  = (const float*)d_in[6];
    const int*   batch = (const int*)d_in[7];

    u16* w1f = (u16*)d_ws;                                        // 256 KB
    u16* w2f = (u16*)((char*)d_ws + (size_t)CIN * HDIM * 2);      // 2 MB
    float* node_e = (float*)((char*)d_ws + (size_t)CIN * HDIM * 2 + (size_t)HDIM * HDIM * 2);

    pack_w<<<64,  256, 0, stream>>>(W1, w1f, CIN,  HDIM);
    pack_w<<<512, 256, 0, stream>>>(W2, w2f, HDIM, HDIM);
    fused_mlp<<<NROWS / BM, 512, 0, stream>>>(emb, w1f, w2f, b1, b2, W3, b3, node_e);
    segsum<<<NMOL, 64, 0, stream>>>(node_e, batch, (float*)d_out);
}